// Round 1
// baseline (1081.788 us; speedup 1.0000x reference)
//
#include <hip/hip_runtime.h>
#include <hip/hip_bf16.h>
#include <stdint.h>

// Problem constants
#define SEQ   8192
#define HDIM  3072
#define NWIN  19
#define WINL  512
#define STR   448
#define NHEAD 12
#define DHEAD 256
#define QKVN  9216
#define ATTN_SCALE 0.0625f

typedef unsigned short u16;
typedef __bf16 bf16x8 __attribute__((ext_vector_type(8)));
typedef float  f32x4  __attribute__((ext_vector_type(4)));
typedef unsigned short us8 __attribute__((ext_vector_type(8)));

__device__ __forceinline__ u16 f2b(float x) {
  return __builtin_bit_cast(u16, __float2bfloat16(x));
}
__device__ __forceinline__ float b2f(u16 u) {
  return __builtin_bit_cast(float, (unsigned int)(u) << 16);
}
__device__ __forceinline__ void gload_lds16(const void* g, void* l) {
  __builtin_amdgcn_global_load_lds(
      (const __attribute__((address_space(1))) void*)g,
      (__attribute__((address_space(3))) void*)l, 16, 0, 0);
}

// ---------------- elementwise converts ----------------
__global__ __launch_bounds__(256) void cvt_f32_bf16(const float* __restrict__ src,
                                                    u16* __restrict__ dst, int n8) {
  int i = blockIdx.x * 256 + threadIdx.x;
  if (i >= n8) return;
  const float4* s4 = (const float4*)src;
  float4 a = s4[2 * i], b = s4[2 * i + 1];
  us8 o;
  o[0] = f2b(a.x); o[1] = f2b(a.y); o[2] = f2b(a.z); o[3] = f2b(a.w);
  o[4] = f2b(b.x); o[5] = f2b(b.y); o[6] = f2b(b.z); o[7] = f2b(b.w);
  *((us8*)dst + i) = o;
}

__global__ __launch_bounds__(256) void biascat(const float* __restrict__ bq,
                                               const float* __restrict__ bk,
                                               const float* __restrict__ bv,
                                               float* __restrict__ dst) {
  int i = blockIdx.x * 256 + threadIdx.x;
  if (i >= QKVN) return;
  dst[i] = (i < HDIM) ? bq[i] : ((i < 2 * HDIM) ? bk[i - HDIM] : bv[i - 2 * HDIM]);
}

// ---------------- m97-style 128x128 GEMM: C = A * B^T (+bias) ----------------
// A[M][K] bf16 row-major, B[N][K] bf16 row-major.
template <bool BF16OUT>
__global__ __launch_bounds__(256) void gemm_bt(const u16* __restrict__ A,
                                               const u16* __restrict__ B,
                                               const float* __restrict__ bias,
                                               float* __restrict__ outF,
                                               u16* __restrict__ outB,
                                               int M, int N, int K) {
  __shared__ __align__(16) u16 As[128 * 32];
  __shared__ __align__(16) u16 Bs[128 * 32];
  const int tid = threadIdx.x;
  const int w = tid >> 6, l = tid & 63;
  const int bm = blockIdx.y, bn = blockIdx.x;
  const int wm = w >> 1, wn = w & 1;
  const int fr = l & 15, g = l >> 4;
  const int srow = l >> 2, scol = (l & 3) * 8;  // staging: 16 rows x 32 cols per 1KB chunk

  f32x4 acc[4][4];
#pragma unroll
  for (int i = 0; i < 4; ++i)
#pragma unroll
    for (int j = 0; j < 4; ++j) acc[i][j] = (f32x4){0.f, 0.f, 0.f, 0.f};

  for (int k0 = 0; k0 < K; k0 += 32) {
#pragma unroll
    for (int j = 0; j < 2; ++j) {
      const int ch = w * 2 + j;  // 0..7 chunk of 1KB (16 rows)
      const int ra = bm * 128 + ch * 16 + srow;
      gload_lds16(A + (size_t)ra * K + k0 + scol, (char*)As + ch * 1024);
      const int rb = bn * 128 + ch * 16 + srow;
      gload_lds16(B + (size_t)rb * K + k0 + scol, (char*)Bs + ch * 1024);
    }
    __syncthreads();
    bf16x8 af[4], bfr[4];
#pragma unroll
    for (int mi = 0; mi < 4; ++mi)
      af[mi] = *(const bf16x8*)(As + (wm * 64 + mi * 16 + fr) * 32 + g * 8);
#pragma unroll
    for (int ni = 0; ni < 4; ++ni)
      bfr[ni] = *(const bf16x8*)(Bs + (wn * 64 + ni * 16 + fr) * 32 + g * 8);
#pragma unroll
    for (int mi = 0; mi < 4; ++mi)
#pragma unroll
      for (int ni = 0; ni < 4; ++ni)
        acc[mi][ni] = __builtin_amdgcn_mfma_f32_16x16x32_bf16(af[mi], bfr[ni], acc[mi][ni], 0, 0, 0);
    __syncthreads();
  }
#pragma unroll
  for (int ni = 0; ni < 4; ++ni) {
    const int c = bn * 128 + wn * 64 + ni * 16 + fr;
    const float bv = bias ? bias[c] : 0.0f;
#pragma unroll
    for (int mi = 0; mi < 4; ++mi) {
      const int r0 = bm * 128 + wm * 64 + mi * 16 + g * 4;
#pragma unroll
      for (int jj = 0; jj < 4; ++jj) {
        float v = acc[mi][ni][jj] + bv;
        if (BF16OUT) outB[(size_t)(r0 + jj) * N + c] = f2b(v);
        else         outF[(size_t)(r0 + jj) * N + c] = v;
      }
    }
  }
}

// ---------------- V transpose: Vt[3072][8192] <- QKV[:, 6144+c] ----------------
__global__ __launch_bounds__(256) void vtrans(const u16* __restrict__ QKV,
                                              u16* __restrict__ Vt) {
  __shared__ u16 t[64][72];
  const int tid = threadIdx.x;
  const int s0 = blockIdx.x * 64, c0 = blockIdx.y * 64;
  {
    const int r2 = tid >> 3, cc = (tid & 7) * 8;
#pragma unroll
    for (int p = 0; p < 2; ++p) {
      const int row = r2 + p * 32;
      u16 tmp[8];
      *(uint4*)tmp = *(const uint4*)(QKV + (size_t)(s0 + row) * QKVN + 2 * HDIM + c0 + cc);
#pragma unroll
      for (int j = 0; j < 8; ++j) t[row][cc + j] = tmp[j];
    }
  }
  __syncthreads();
  {
    const int cr2 = tid >> 3, sc = tid & 7;
#pragma unroll
    for (int p = 0; p < 2; ++p) {
      const int c = cr2 + p * 32;
      u16 tmp[8];
#pragma unroll
      for (int j = 0; j < 8; ++j) tmp[j] = t[sc * 8 + j][c];
      *(uint4*)(Vt + (size_t)(c0 + c) * SEQ + s0 + sc * 8) = *(uint4*)tmp;
    }
  }
}

// ---------------- windowed flash attention ----------------
// grid (8 qb, 12 h, 19 win), 4 waves. Each wave: 16 q-rows, online softmax over 8 chunks of 64 kv.
__global__ __launch_bounds__(256, 2) void attn_kernel(const u16* __restrict__ QKV,
                                                      const u16* __restrict__ Vt,
                                                      u16* __restrict__ ctxw) {
  __shared__ __align__(16) u16 Ks[64 * 256];   // [kv][d], chunk-swizzled (XOR row&31 on 16B chunks)
  __shared__ __align__(16) u16 Vts[256 * 64];  // [d][kv], chunk-swizzled (XOR row&7)
  __shared__ __align__(16) u16 Ps[4][16 * 64]; // per-wave P scratch, XOR (q&7)<<4 byte swizzle
  const int qb = blockIdx.x, h = blockIdx.y, n = blockIdx.z;
  const int tid = threadIdx.x, w = tid >> 6, l = tid & 63;
  const int g = l >> 4, fr = l & 15;
  const int s0 = n * STR;

  // Q fragments (16 rows per wave) straight from global
  bf16x8 qf[8];
  {
    int sq = s0 + qb * 64 + w * 16 + fr;
    if (sq > SEQ - 1) sq = SEQ - 1;
    const u16* qbase = QKV + (size_t)sq * QKVN + h * DHEAD + g * 8;
#pragma unroll
    for (int dc = 0; dc < 8; ++dc) qf[dc] = *(const bf16x8*)(qbase + dc * 32);
  }
  f32x4 ctx[16];
#pragma unroll
  for (int dn = 0; dn < 16; ++dn) ctx[dn] = (f32x4){0.f, 0.f, 0.f, 0.f};
  float mrow[4] = {-3e38f, -3e38f, -3e38f, -3e38f};
  float lrow[4] = {0.f, 0.f, 0.f, 0.f};

  const int kr_in = l >> 5;  // K staging: row within 2-row chunk
  const int kcp = l & 31;    // K staging: physical 16B chunk in row
  const int vr_in = l >> 3;  // V staging: row within 8-row chunk
  const int vcp = l & 7;

  for (int kt = 0; kt < 8; ++kt) {
    const int sb = s0 + kt * 64;
    // ---- stage K[64][256] and Vt-slice[256][64], source pre-swizzled ----
#pragma unroll
    for (int i = 0; i < 8; ++i) {
      const int c = i * 4 + w;  // 1KB chunk id, 0..31
      {
        const int krow = c * 2 + kr_in;
        const int cl = kcp ^ (krow & 31);
        int sk = sb + krow;
        if (sk > SEQ - 1) sk = SEQ - 1;
        gload_lds16(QKV + (size_t)sk * QKVN + HDIM + h * DHEAD + cl * 8, (char*)Ks + c * 1024);
      }
      {
        const int d = c * 8 + vr_in;
        const int cl = vcp ^ (d & 7);
        int sv = sb + cl * 8;
        if (sv > SEQ - 8) sv = SEQ - 8;
        gload_lds16(Vt + (size_t)(h * DHEAD + d) * SEQ + sv, (char*)Vts + c * 1024);
      }
    }
    __syncthreads();

    // ---- S = Q K^T (rows q=(g*4+r), cols kv=kn*16+fr) ----
    f32x4 sacc[4];
#pragma unroll
    for (int kn = 0; kn < 4; ++kn) sacc[kn] = (f32x4){0.f, 0.f, 0.f, 0.f};
#pragma unroll
    for (int kn = 0; kn < 4; ++kn) {
      const int krow = kn * 16 + fr;
      const char* krp = (const char*)Ks + krow * 512;
      const int rx = krow & 31;
#pragma unroll
      for (int dc = 0; dc < 8; ++dc) {
        bf16x8 kf = *(const bf16x8*)(krp + (((dc * 4 + g) ^ rx) << 4));
        sacc[kn] = __builtin_amdgcn_mfma_f32_16x16x32_bf16(qf[dc], kf, sacc[kn], 0, 0, 0);
      }
    }
    // ---- scale + validity mask + online softmax ----
    float mt[4];
#pragma unroll
    for (int kn = 0; kn < 4; ++kn) {
      const bool valid = (sb + kn * 16 + fr) < SEQ;
#pragma unroll
      for (int r = 0; r < 4; ++r) {
        float v = valid ? sacc[kn][r] * ATTN_SCALE : -1e9f;
        sacc[kn][r] = v;
        mt[r] = (kn == 0) ? v : fmaxf(mt[r], v);
      }
    }
#pragma unroll
    for (int r = 0; r < 4; ++r) {
#pragma unroll
      for (int off = 1; off < 16; off <<= 1)
        mt[r] = fmaxf(mt[r], __shfl_xor(mt[r], off, 64));
    }
    float corr[4];
#pragma unroll
    for (int r = 0; r < 4; ++r) {
      float mnew = fmaxf(mrow[r], mt[r]);
      corr[r] = __expf(mrow[r] - mnew);
      mrow[r] = mnew;
    }
    float psum[4] = {0.f, 0.f, 0.f, 0.f};
    char* pw = (char*)&Ps[w][0];
#pragma unroll
    for (int kn = 0; kn < 4; ++kn) {
#pragma unroll
      for (int r = 0; r < 4; ++r) {
        float p = __expf(sacc[kn][r] - mrow[r]);
        psum[r] += p;
        const int q = g * 4 + r;
        *(u16*)(pw + q * 128 + ((2 * (kn * 16 + fr)) ^ ((q & 7) << 4))) = f2b(p);
      }
    }
#pragma unroll
    for (int r = 0; r < 4; ++r) {
#pragma unroll
      for (int off = 1; off < 16; off <<= 1)
        psum[r] += __shfl_xor(psum[r], off, 64);
      lrow[r] = lrow[r] * corr[r] + psum[r];
    }
#pragma unroll
    for (int dn = 0; dn < 16; ++dn)
#pragma unroll
      for (int r = 0; r < 4; ++r) ctx[dn][r] *= corr[r];
    __syncthreads();  // Ps visible (and ordered) before fragment reads

    // ---- ctx += P * V (via Vt rows as B^T) ----
    bf16x8 pf[2];
#pragma unroll
    for (int kc = 0; kc < 2; ++kc)
      pf[kc] = *(const bf16x8*)(pw + fr * 128 + ((kc * 64 + g * 16) ^ ((fr & 7) << 4)));
#pragma unroll
    for (int dn = 0; dn < 16; ++dn) {
      const int d = dn * 16 + fr;
      const char* vrp = (const char*)Vts + d * 128;
      const int dx = d & 7;
#pragma unroll
      for (int kc = 0; kc < 2; ++kc) {
        bf16x8 vf = *(const bf16x8*)(vrp + (((kc * 4 + g) ^ dx) << 4));
        ctx[dn] = __builtin_amdgcn_mfma_f32_16x16x32_bf16(pf[kc], vf, ctx[dn], 0, 0, 0);
      }
    }
    __syncthreads();  // all waves done with Ks/Vts before next stage
  }
  // ---- epilogue: normalize and store ctx ----
  float inv[4];
#pragma unroll
  for (int r = 0; r < 4; ++r) inv[r] = 1.0f / lrow[r];
  const int qrow0 = qb * 64 + w * 16 + g * 4;
#pragma unroll
  for (int dn = 0; dn < 16; ++dn) {
#pragma unroll
    for (int r = 0; r < 4; ++r) {
      ctxw[(size_t)(n * WINL + qrow0 + r) * HDIM + h * DHEAD + dn * 16 + fr] =
          f2b(ctx[dn][r] * inv[r]);
    }
  }
}

// ---------------- overlap-average combine: ctx_avg[8192][3072] ----------------
__global__ __launch_bounds__(256) void combine_kernel(const u16* __restrict__ ctxw,
                                                      u16* __restrict__ ctx_avg) {
  int idx = blockIdx.x * 256 + threadIdx.x;
  if (idx >= SEQ * (HDIM / 8)) return;
  const int s = idx / (HDIM / 8);
  const int cc = (idx % (HDIM / 8)) * 8;
  const int w1 = s / STR;          // <= 18
  const int off1 = s - w1 * STR;   // 0..447
  us8 a = *(const us8*)(ctxw + (size_t)(w1 * WINL + off1) * HDIM + cc);
  if (w1 >= 1 && off1 < (WINL - STR)) {
    us8 b = *(const us8*)(ctxw + (size_t)((w1 - 1) * WINL + off1 + STR) * HDIM + cc);
#pragma unroll
    for (int j = 0; j < 8; ++j) a[j] = f2b(0.5f * (b2f(a[j]) + b2f(b[j])));
  }
  *(us8*)(ctx_avg + (size_t)s * HDIM + cc) = a;
}

__global__ void ws_marker(float* out, float v) { out[0] = v; }

// ---------------- launch ----------------
extern "C" void kernel_launch(void* const* d_in, const int* in_sizes, int n_in,
                              void* d_out, int out_size, void* d_ws, size_t ws_size,
                              hipStream_t stream) {
  const float* X  = (const float*)d_in[0];
  const float* Wq = (const float*)d_in[1];
  const float* bq = (const float*)d_in[2];
  const float* Wk = (const float*)d_in[3];
  const float* bk = (const float*)d_in[4];
  const float* Wv = (const float*)d_in[5];
  const float* bv = (const float*)d_in[6];
  const float* Wo = (const float*)d_in[7];
  const float* bo = (const float*)d_in[8];
  float* out = (float*)d_out;

  // workspace layout (bytes)
  const size_t OFF_XB   = 0;                          // 8192*3072*2   = 50331648
  const size_t OFF_WQKV = 50331648;                   // 9216*3072*2   = 56623104
  const size_t OFF_WO   = 106954752;                  // 3072*3072*2   = 18874368
  const size_t OFF_QKV  = 125829120;                  // 8192*9216*2   = 150994944
  const size_t OFF_VT   = 276824064;                  // 3072*8192*2   = 50331648
  const size_t OFF_BIAS = 327155712;                  // 9216*4        = 36864
  const size_t WS_NEED  = 327192576;
  if (ws_size < WS_NEED) {
    // diagnostic: absmax will read ~ws_size in MB
    hipMemsetAsync(d_out, 0, (size_t)out_size * 4, stream);
    ws_marker<<<1, 1, 0, stream>>>(out, (float)(ws_size / 1048576));
    return;
  }
  char* ws = (char*)d_ws;
  u16* Xb      = (u16*)(ws + OFF_XB);
  u16* Wqkvb   = (u16*)(ws + OFF_WQKV);
  u16* Wob     = (u16*)(ws + OFF_WO);
  u16* QKV     = (u16*)(ws + OFF_QKV);
  u16* Vt      = (u16*)(ws + OFF_VT);
  float* biasQ = (float*)(ws + OFF_BIAS);
  u16* ctxw    = (u16*)d_out;  // 59.8MB scratch inside the 100.7MB output buffer
  u16* ctx_avg = Xb;           // alias: Xb dead after QKV GEMM

  cvt_f32_bf16<<<12288, 256, 0, stream>>>(X, Xb, SEQ * HDIM / 8);
  cvt_f32_bf16<<<4608, 256, 0, stream>>>(Wq, Wqkvb, HDIM * HDIM / 8);
  cvt_f32_bf16<<<4608, 256, 0, stream>>>(Wk, Wqkvb + (size_t)HDIM * HDIM, HDIM * HDIM / 8);
  cvt_f32_bf16<<<4608, 256, 0, stream>>>(Wv, Wqkvb + (size_t)2 * HDIM * HDIM, HDIM * HDIM / 8);
  cvt_f32_bf16<<<4608, 256, 0, stream>>>(Wo, Wob, HDIM * HDIM / 8);
  biascat<<<36, 256, 0, stream>>>(bq, bk, bv, biasQ);

  gemm_bt<true><<<dim3(QKVN / 128, SEQ / 128), 256, 0, stream>>>(
      Xb, Wqkvb, biasQ, nullptr, QKV, SEQ, QKVN, HDIM);

  vtrans<<<dim3(SEQ / 64, HDIM / 64), 256, 0, stream>>>(QKV, Vt);

  attn_kernel<<<dim3(8, NHEAD, NWIN), 256, 0, stream>>>(QKV, Vt, ctxw);

  combine_kernel<<<12288, 256, 0, stream>>>(ctxw, ctx_avg);

  gemm_bt<false><<<dim3(HDIM / 128, SEQ / 128), 256, 0, stream>>>(
      ctx_avg, Wob, bo, out, nullptr, SEQ, HDIM, HDIM);
}

// Round 2
// 993.993 us; speedup vs baseline: 1.0883x; 1.0883x over previous
//
#include <hip/hip_runtime.h>
#include <hip/hip_bf16.h>
#include <stdint.h>

// Problem constants
#define SEQ   8192
#define HDIM  3072
#define NWIN  19
#define WINL  512
#define STR   448
#define NHEAD 12
#define DHEAD 256
#define QKVN  9216
#define ATTN_SCALE 0.0625f

typedef unsigned short u16;
typedef __bf16 bf16x8 __attribute__((ext_vector_type(8)));
typedef float  f32x4  __attribute__((ext_vector_type(4)));
typedef unsigned short us8 __attribute__((ext_vector_type(8)));

__device__ __forceinline__ u16 f2b(float x) {
  return __builtin_bit_cast(u16, __float2bfloat16(x));
}
__device__ __forceinline__ float b2f(u16 u) {
  return __builtin_bit_cast(float, (unsigned int)(u) << 16);
}
__device__ __forceinline__ void gload_lds16(const void* g, void* l) {
  __builtin_amdgcn_global_load_lds(
      (const __attribute__((address_space(1))) void*)g,
      (__attribute__((address_space(3))) void*)l, 16, 0, 0);
}

// ---------------- elementwise converts ----------------
__global__ __launch_bounds__(256) void cvt_f32_bf16(const float* __restrict__ src,
                                                    u16* __restrict__ dst, int n8) {
  int i = blockIdx.x * 256 + threadIdx.x;
  if (i >= n8) return;
  const float4* s4 = (const float4*)src;
  float4 a = s4[2 * i], b = s4[2 * i + 1];
  us8 o;
  o[0] = f2b(a.x); o[1] = f2b(a.y); o[2] = f2b(a.z); o[3] = f2b(a.w);
  o[4] = f2b(b.x); o[5] = f2b(b.y); o[6] = f2b(b.z); o[7] = f2b(b.w);
  *((us8*)dst + i) = o;
}

__global__ __launch_bounds__(256) void biascat(const float* __restrict__ bq,
                                               const float* __restrict__ bk,
                                               const float* __restrict__ bv,
                                               float* __restrict__ dst) {
  int i = blockIdx.x * 256 + threadIdx.x;
  if (i >= QKVN) return;
  dst[i] = (i < HDIM) ? bq[i] : ((i < 2 * HDIM) ? bk[i - HDIM] : bv[i - 2 * HDIM]);
}

// ---------------- 256x256 pipelined GEMM: C = A * B^T (+bias) ----------------
// A[M][K] bf16 row-major, B[N][K] bf16 row-major. BK=32, 8 waves (2Mx4N),
// per-wave C = 128x64. LDS: ring of 4 half-slots (128x32) per operand, 64 KiB.
// Schedule per K-tile T (2 phases):
//   q0: ds_read 12 frags (A mi0-7, B ni0-3) | stage B-halves of T+1 | bar |
//       setprio1 16xMFMA(mi0-3) setprio0 | bar
//   q1: stage A-halves of T+2 | bar | setprio1 16xMFMA(mi4-7) setprio0 |
//       s_waitcnt vmcnt(2) | bar
// Race-freedom: tile-T LDS is ds_read only in q0 (drained before q0's MFMA);
// staging T+2 into T's slots happens in q1, after q0's end barrier.
// vmcnt(2): at tile boundary exactly T+2's two A-half loads are in flight.
template <bool BF16OUT>
__global__ __launch_bounds__(512, 2) void gemm256(const u16* __restrict__ A,
                                                  const u16* __restrict__ B,
                                                  const float* __restrict__ bias,
                                                  float* __restrict__ outF,
                                                  u16* __restrict__ outB,
                                                  int M, int N, int K, int nbn) {
  __shared__ __align__(16) u16 As[4][4096];
  __shared__ __align__(16) u16 Bs[4][4096];
  const int tid = threadIdx.x;
  const int w = tid >> 6, l = tid & 63;
  const int wm = w >> 2, wn = w & 3;
  const int fr = l & 15, g = l >> 4;
  // T1: XCD-aware bijective swizzle (grid % 8 == 0 guaranteed by caller)
  const int nwg = gridDim.x;
  const int bid = blockIdx.x;
  const int wg = (bid & 7) * (nwg >> 3) + (bid >> 3);
  const int bm = wg / nbn, bn = wg % nbn;

  const u16* Ab = A + (size_t)bm * 256 * K;
  const u16* Bb = B + (size_t)bn * 256 * K;

  // staging thread mapping: thread writes LDS bytes w*1024 + l*16 of an 8KB half
  // -> row r_st = w*16 + (l>>2), physical 16B slot (l&3); logical slot = phys ^ ((r>>1)&3)
  const int r_st = w * 16 + (l >> 2);
  const int s_st = ((l & 3) ^ ((l >> 3) & 3)) * 8;  // element offset of logical col
  // fragment read swizzle: physical slot = g ^ ((row>>1)&3); row%8 == fr%8 everywhere
  const int sw = (g ^ ((fr >> 1) & 3)) * 8;

  f32x4 acc[8][4];
#pragma unroll
  for (int i = 0; i < 8; ++i)
#pragma unroll
    for (int j = 0; j < 4; ++j) acc[i][j] = (f32x4){0.f, 0.f, 0.f, 0.f};

  auto stA = [&](int U, int h) {
    gload_lds16(Ab + (size_t)(h * 128 + r_st) * K + U * 32 + s_st,
                (char*)&As[(2 * U + h) & 3][0] + w * 1024);
  };
  auto stB = [&](int U, int h) {
    gload_lds16(Bb + (size_t)(h * 128 + r_st) * K + U * 32 + s_st,
                (char*)&Bs[(2 * U + h) & 3][0] + w * 1024);
  };

  // prologue: tile0 (A0,A1,B0,B1), tile1 (A0,A1); wait oldest 4 -> tile0 ready
  stA(0, 0); stA(0, 1); stB(0, 0); stB(0, 1); stA(1, 0); stA(1, 1);
  asm volatile("s_waitcnt vmcnt(2)" ::: "memory");
  __builtin_amdgcn_s_barrier();
  __builtin_amdgcn_sched_barrier(0);

  const int NT = K >> 5;

  auto step = [&](int T, bool doB, bool doA, int vm) {
    const u16* ap = &As[(2 * T + wm) & 3][0] + fr * 32 + sw;
    const u16* bp = &Bs[(2 * T + (wn >> 1)) & 3][0] + (wn & 1) * 64 * 32 + fr * 32 + sw;
    bf16x8 af[8], bf[4];
#pragma unroll
    for (int mi = 0; mi < 8; ++mi) af[mi] = *(const bf16x8*)(ap + mi * 512);
#pragma unroll
    for (int ni = 0; ni < 4; ++ni) bf[ni] = *(const bf16x8*)(bp + ni * 512);
    if (doB) { stB(T + 1, 0); stB(T + 1, 1); }
    __builtin_amdgcn_s_barrier();
    __builtin_amdgcn_s_setprio(1);
#pragma unroll
    for (int mi = 0; mi < 4; ++mi)
#pragma unroll
      for (int ni = 0; ni < 4; ++ni)
        acc[mi][ni] = __builtin_amdgcn_mfma_f32_16x16x32_bf16(af[mi], bf[ni], acc[mi][ni], 0, 0, 0);
    __builtin_amdgcn_s_setprio(0);
    __builtin_amdgcn_s_barrier();
    if (doA) { stA(T + 2, 0); stA(T + 2, 1); }
    __builtin_amdgcn_s_barrier();
    __builtin_amdgcn_s_setprio(1);
#pragma unroll
    for (int mi = 4; mi < 8; ++mi)
#pragma unroll
      for (int ni = 0; ni < 4; ++ni)
        acc[mi][ni] = __builtin_amdgcn_mfma_f32_16x16x32_bf16(af[mi], bf[ni], acc[mi][ni], 0, 0, 0);
    __builtin_amdgcn_s_setprio(0);
    if (vm == 2) asm volatile("s_waitcnt vmcnt(2)" ::: "memory");
    else if (vm == 0) asm volatile("s_waitcnt vmcnt(0)" ::: "memory");
    __builtin_amdgcn_s_barrier();
    __builtin_amdgcn_sched_barrier(0);
  };

#pragma unroll 2
  for (int T = 0; T < NT - 2; ++T) step(T, true, true, 2);
  step(NT - 2, true, false, 0);
  step(NT - 1, false, false, -1);

  // epilogue
#pragma unroll
  for (int ni = 0; ni < 4; ++ni) {
    const int c = bn * 256 + wn * 64 + ni * 16 + fr;
    const float bvv = bias ? bias[c] : 0.0f;
#pragma unroll
    for (int mi = 0; mi < 8; ++mi) {
      const int r0 = bm * 256 + wm * 128 + mi * 16 + g * 4;
#pragma unroll
      for (int jj = 0; jj < 4; ++jj) {
        float v = acc[mi][ni][jj] + bvv;
        if (BF16OUT) outB[(size_t)(r0 + jj) * N + c] = f2b(v);
        else         outF[(size_t)(r0 + jj) * N + c] = v;
      }
    }
  }
}

// ---------------- V transpose: Vt[3072][8192] <- QKV[:, 6144+c] ----------------
__global__ __launch_bounds__(256) void vtrans(const u16* __restrict__ QKV,
                                              u16* __restrict__ Vt) {
  __shared__ u16 t[64][72];
  const int tid = threadIdx.x;
  const int s0 = blockIdx.x * 64, c0 = blockIdx.y * 64;
  {
    const int r2 = tid >> 3, cc = (tid & 7) * 8;
#pragma unroll
    for (int p = 0; p < 2; ++p) {
      const int row = r2 + p * 32;
      u16 tmp[8];
      *(uint4*)tmp = *(const uint4*)(QKV + (size_t)(s0 + row) * QKVN + 2 * HDIM + c0 + cc);
#pragma unroll
      for (int j = 0; j < 8; ++j) t[row][cc + j] = tmp[j];
    }
  }
  __syncthreads();
  {
    const int cr2 = tid >> 3, sc = tid & 7;
#pragma unroll
    for (int p = 0; p < 2; ++p) {
      const int c = cr2 + p * 32;
      u16 tmp[8];
#pragma unroll
      for (int j = 0; j < 8; ++j) tmp[j] = t[sc * 8 + j][c];
      *(uint4*)(Vt + (size_t)(c0 + c) * SEQ + s0 + sc * 8) = *(uint4*)tmp;
    }
  }
}

// ---------------- windowed flash attention ----------------
// grid (8 qb, 12 h, 19 win), 4 waves. Each wave: 16 q-rows, online softmax over 8 chunks of 64 kv.
__global__ __launch_bounds__(256, 2) void attn_kernel(const u16* __restrict__ QKV,
                                                      const u16* __restrict__ Vt,
                                                      u16* __restrict__ ctxw) {
  __shared__ __align__(16) u16 Ks[64 * 256];   // [kv][d], chunk-swizzled (XOR row&31 on 16B chunks)
  __shared__ __align__(16) u16 Vts[256 * 64];  // [d][kv], chunk-swizzled (XOR row&7)
  __shared__ __align__(16) u16 Ps[4][16 * 64]; // per-wave P scratch, XOR (q&7)<<4 byte swizzle
  const int qb = blockIdx.x, h = blockIdx.y, n = blockIdx.z;
  const int tid = threadIdx.x, w = tid >> 6, l = tid & 63;
  const int g = l >> 4, fr = l & 15;
  const int s0 = n * STR;

  // Q fragments (16 rows per wave) straight from global
  bf16x8 qf[8];
  {
    int sq = s0 + qb * 64 + w * 16 + fr;
    if (sq > SEQ - 1) sq = SEQ - 1;
    const u16* qbase = QKV + (size_t)sq * QKVN + h * DHEAD + g * 8;
#pragma unroll
    for (int dc = 0; dc < 8; ++dc) qf[dc] = *(const bf16x8*)(qbase + dc * 32);
  }
  f32x4 ctx[16];
#pragma unroll
  for (int dn = 0; dn < 16; ++dn) ctx[dn] = (f32x4){0.f, 0.f, 0.f, 0.f};
  float mrow[4] = {-3e38f, -3e38f, -3e38f, -3e38f};
  float lrow[4] = {0.f, 0.f, 0.f, 0.f};

  const int kr_in = l >> 5;  // K staging: row within 2-row chunk
  const int kcp = l & 31;    // K staging: physical 16B chunk in row
  const int vr_in = l >> 3;  // V staging: row within 8-row chunk
  const int vcp = l & 7;

  for (int kt = 0; kt < 8; ++kt) {
    const int sb = s0 + kt * 64;
    // ---- stage K[64][256] and Vt-slice[256][64], source pre-swizzled ----
#pragma unroll
    for (int i = 0; i < 8; ++i) {
      const int c = i * 4 + w;  // 1KB chunk id, 0..31
      {
        const int krow = c * 2 + kr_in;
        const int cl = kcp ^ (krow & 31);
        int sk = sb + krow;
        if (sk > SEQ - 1) sk = SEQ - 1;
        gload_lds16(QKV + (size_t)sk * QKVN + HDIM + h * DHEAD + cl * 8, (char*)Ks + c * 1024);
      }
      {
        const int d = c * 8 + vr_in;
        const int cl = vcp ^ (d & 7);
        int sv = sb + cl * 8;
        if (sv > SEQ - 8) sv = SEQ - 8;
        gload_lds16(Vt + (size_t)(h * DHEAD + d) * SEQ + sv, (char*)Vts + c * 1024);
      }
    }
    __syncthreads();

    // ---- S = Q K^T (rows q=(g*4+r), cols kv=kn*16+fr) ----
    f32x4 sacc[4];
#pragma unroll
    for (int kn = 0; kn < 4; ++kn) sacc[kn] = (f32x4){0.f, 0.f, 0.f, 0.f};
#pragma unroll
    for (int kn = 0; kn < 4; ++kn) {
      const int krow = kn * 16 + fr;
      const char* krp = (const char*)Ks + krow * 512;
      const int rx = krow & 31;
#pragma unroll
      for (int dc = 0; dc < 8; ++dc) {
        bf16x8 kf = *(const bf16x8*)(krp + (((dc * 4 + g) ^ rx) << 4));
        sacc[kn] = __builtin_amdgcn_mfma_f32_16x16x32_bf16(qf[dc], kf, sacc[kn], 0, 0, 0);
      }
    }
    // ---- scale + validity mask + online softmax ----
    float mt[4];
#pragma unroll
    for (int kn = 0; kn < 4; ++kn) {
      const bool valid = (sb + kn * 16 + fr) < SEQ;
#pragma unroll
      for (int r = 0; r < 4; ++r) {
        float v = valid ? sacc[kn][r] * ATTN_SCALE : -1e9f;
        sacc[kn][r] = v;
        mt[r] = (kn == 0) ? v : fmaxf(mt[r], v);
      }
    }
#pragma unroll
    for (int r = 0; r < 4; ++r) {
#pragma unroll
      for (int off = 1; off < 16; off <<= 1)
        mt[r] = fmaxf(mt[r], __shfl_xor(mt[r], off, 64));
    }
    float corr[4];
#pragma unroll
    for (int r = 0; r < 4; ++r) {
      float mnew = fmaxf(mrow[r], mt[r]);
      corr[r] = __expf(mrow[r] - mnew);
      mrow[r] = mnew;
    }
    float psum[4] = {0.f, 0.f, 0.f, 0.f};
    char* pw = (char*)&Ps[w][0];
#pragma unroll
    for (int kn = 0; kn < 4; ++kn) {
#pragma unroll
      for (int r = 0; r < 4; ++r) {
        float p = __expf(sacc[kn][r] - mrow[r]);
        psum[r] += p;
        const int q = g * 4 + r;
        *(u16*)(pw + q * 128 + ((2 * (kn * 16 + fr)) ^ ((q & 7) << 4))) = f2b(p);
      }
    }
#pragma unroll
    for (int r = 0; r < 4; ++r) {
#pragma unroll
      for (int off = 1; off < 16; off <<= 1)
        psum[r] += __shfl_xor(psum[r], off, 64);
      lrow[r] = lrow[r] * corr[r] + psum[r];
    }
#pragma unroll
    for (int dn = 0; dn < 16; ++dn)
#pragma unroll
      for (int r = 0; r < 4; ++r) ctx[dn][r] *= corr[r];
    __syncthreads();  // Ps visible (and ordered) before fragment reads

    // ---- ctx += P * V (via Vt rows as B^T) ----
    bf16x8 pf[2];
#pragma unroll
    for (int kc = 0; kc < 2; ++kc)
      pf[kc] = *(const bf16x8*)(pw + fr * 128 + ((kc * 64 + g * 16) ^ ((fr & 7) << 4)));
#pragma unroll
    for (int dn = 0; dn < 16; ++dn) {
      const int d = dn * 16 + fr;
      const char* vrp = (const char*)Vts + d * 128;
      const int dx = d & 7;
#pragma unroll
      for (int kc = 0; kc < 2; ++kc) {
        bf16x8 vf = *(const bf16x8*)(vrp + (((kc * 4 + g) ^ dx) << 4));
        ctx[dn] = __builtin_amdgcn_mfma_f32_16x16x32_bf16(pf[kc], vf, ctx[dn], 0, 0, 0);
      }
    }
    __syncthreads();  // all waves done with Ks/Vts before next stage
  }
  // ---- epilogue: normalize and store ctx ----
  float inv[4];
#pragma unroll
  for (int r = 0; r < 4; ++r) inv[r] = 1.0f / lrow[r];
  const int qrow0 = qb * 64 + w * 16 + g * 4;
#pragma unroll
  for (int dn = 0; dn < 16; ++dn) {
#pragma unroll
    for (int r = 0; r < 4; ++r) {
      ctxw[(size_t)(n * WINL + qrow0 + r) * HDIM + h * DHEAD + dn * 16 + fr] =
          f2b(ctx[dn][r] * inv[r]);
    }
  }
}

// ---------------- overlap-average combine: ctx_avg[8192][3072] ----------------
__global__ __launch_bounds__(256) void combine_kernel(const u16* __restrict__ ctxw,
                                                      u16* __restrict__ ctx_avg) {
  int idx = blockIdx.x * 256 + threadIdx.x;
  if (idx >= SEQ * (HDIM / 8)) return;
  const int s = idx / (HDIM / 8);
  const int cc = (idx % (HDIM / 8)) * 8;
  const int w1 = s / STR;          // <= 18
  const int off1 = s - w1 * STR;   // 0..447
  us8 a = *(const us8*)(ctxw + (size_t)(w1 * WINL + off1) * HDIM + cc);
  if (w1 >= 1 && off1 < (WINL - STR)) {
    us8 b = *(const us8*)(ctxw + (size_t)((w1 - 1) * WINL + off1 + STR) * HDIM + cc);
#pragma unroll
    for (int j = 0; j < 8; ++j) a[j] = f2b(0.5f * (b2f(a[j]) + b2f(b[j])));
  }
  *(us8*)(ctx_avg + (size_t)s * HDIM + cc) = a;
}

__global__ void ws_marker(float* out, float v) { out[0] = v; }

// ---------------- launch ----------------
extern "C" void kernel_launch(void* const* d_in, const int* in_sizes, int n_in,
                              void* d_out, int out_size, void* d_ws, size_t ws_size,
                              hipStream_t stream) {
  const float* X  = (const float*)d_in[0];
  const float* Wq = (const float*)d_in[1];
  const float* bq = (const float*)d_in[2];
  const float* Wk = (const float*)d_in[3];
  const float* bk = (const float*)d_in[4];
  const float* Wv = (const float*)d_in[5];
  const float* bv = (const float*)d_in[6];
  const float* Wo = (const float*)d_in[7];
  const float* bo = (const float*)d_in[8];
  float* out = (float*)d_out;

  // workspace layout (bytes)
  const size_t OFF_XB   = 0;                          // 8192*3072*2   = 50331648
  const size_t OFF_WQKV = 50331648;                   // 9216*3072*2   = 56623104
  const size_t OFF_WO   = 106954752;                  // 3072*3072*2   = 18874368
  const size_t OFF_QKV  = 125829120;                  // 8192*9216*2   = 150994944
  const size_t OFF_VT   = 276824064;                  // 3072*8192*2   = 50331648
  const size_t OFF_BIAS = 327155712;                  // 9216*4        = 36864
  const size_t WS_NEED  = 327192576;
  if (ws_size < WS_NEED) {
    hipMemsetAsync(d_out, 0, (size_t)out_size * 4, stream);
    ws_marker<<<1, 1, 0, stream>>>(out, (float)(ws_size / 1048576));
    return;
  }
  char* ws = (char*)d_ws;
  u16* Xb      = (u16*)(ws + OFF_XB);
  u16* Wqkvb   = (u16*)(ws + OFF_WQKV);
  u16* Wob     = (u16*)(ws + OFF_WO);
  u16* QKV     = (u16*)(ws + OFF_QKV);
  u16* Vt      = (u16*)(ws + OFF_VT);
  float* biasQ = (float*)(ws + OFF_BIAS);
  u16* ctxw    = (u16*)d_out;  // 59.8MB scratch inside the 100.7MB output buffer
  u16* ctx_avg = Xb;           // alias: Xb dead after QKV GEMM

  cvt_f32_bf16<<<12288, 256, 0, stream>>>(X, Xb, SEQ * HDIM / 8);
  cvt_f32_bf16<<<4608, 256, 0, stream>>>(Wq, Wqkvb, HDIM * HDIM / 8);
  cvt_f32_bf16<<<4608, 256, 0, stream>>>(Wk, Wqkvb + (size_t)HDIM * HDIM, HDIM * HDIM / 8);
  cvt_f32_bf16<<<4608, 256, 0, stream>>>(Wv, Wqkvb + (size_t)2 * HDIM * HDIM, HDIM * HDIM / 8);
  cvt_f32_bf16<<<4608, 256, 0, stream>>>(Wo, Wob, HDIM * HDIM / 8);
  biascat<<<36, 256, 0, stream>>>(bq, bk, bv, biasQ);

  gemm256<true><<<dim3((SEQ / 256) * (QKVN / 256)), 512, 0, stream>>>(
      Xb, Wqkvb, biasQ, nullptr, QKV, SEQ, QKVN, HDIM, QKVN / 256);

  vtrans<<<dim3(SEQ / 64, HDIM / 64), 256, 0, stream>>>(QKV, Vt);

  attn_kernel<<<dim3(8, NHEAD, NWIN), 256, 0, stream>>>(QKV, Vt, ctxw);

  combine_kernel<<<12288, 256, 0, stream>>>(ctxw, ctx_avg);

  gemm256<false><<<dim3((SEQ / 256) * (HDIM / 256)), 512, 0, stream>>>(
      ctx_avg, Wob, bo, out, nullptr, SEQ, HDIM, HDIM, HDIM / 256);
}

// Round 3
// 951.237 us; speedup vs baseline: 1.1372x; 1.0449x over previous
//
#include <hip/hip_runtime.h>
#include <hip/hip_bf16.h>
#include <stdint.h>

// Problem constants
#define SEQ   8192
#define HDIM  3072
#define NWIN  19
#define WINL  512
#define STR   448
#define NHEAD 12
#define DHEAD 256
#define QKVN  9216
#define ATTN_SCALE 0.0625f

typedef unsigned short u16;
typedef __bf16 bf16x8 __attribute__((ext_vector_type(8)));
typedef float  f32x4  __attribute__((ext_vector_type(4)));
typedef unsigned short us8 __attribute__((ext_vector_type(8)));

__device__ __forceinline__ u16 f2b(float x) {
  return __builtin_bit_cast(u16, __float2bfloat16(x));
}
__device__ __forceinline__ float b2f(u16 u) {
  return __builtin_bit_cast(float, (unsigned int)(u) << 16);
}
__device__ __forceinline__ void gload_lds16(const void* g, void* l) {
  __builtin_amdgcn_global_load_lds(
      (const __attribute__((address_space(1))) void*)g,
      (__attribute__((address_space(3))) void*)l, 16, 0, 0);
}

// ---------------- elementwise converts ----------------
__global__ __launch_bounds__(256) void cvt_f32_bf16(const float* __restrict__ src,
                                                    u16* __restrict__ dst, int n8) {
  int i = blockIdx.x * 256 + threadIdx.x;
  if (i >= n8) return;
  const float4* s4 = (const float4*)src;
  float4 a = s4[2 * i], b = s4[2 * i + 1];
  us8 o;
  o[0] = f2b(a.x); o[1] = f2b(a.y); o[2] = f2b(a.z); o[3] = f2b(a.w);
  o[4] = f2b(b.x); o[5] = f2b(b.y); o[6] = f2b(b.z); o[7] = f2b(b.w);
  *((us8*)dst + i) = o;
}

__global__ __launch_bounds__(256) void biascat(const float* __restrict__ bq,
                                               const float* __restrict__ bk,
                                               const float* __restrict__ bv,
                                               float* __restrict__ dst) {
  int i = blockIdx.x * 256 + threadIdx.x;
  if (i >= QKVN) return;
  dst[i] = (i < HDIM) ? bq[i] : ((i < 2 * HDIM) ? bk[i - HDIM] : bv[i - 2 * HDIM]);
}

// ---------------- 256x256 deep-pipelined GEMM: C = A * B^T (+bias) ----------------
// A[M][K] bf16 row-major, B[N][K] bf16 row-major. K-subtile = BK=32.
// 8 waves (2Mx4N), per-wave C = 128x64. LDS: ring of 4 subtile slots [256][32]
// per operand = 128 KiB. Compute T reads slot T%4; stage T+3 -> slot (T-1)%4
// (reads of T-1 finished before T's opening barrier -> race-free).
// vmcnt(8) once per subtile: drains T+1 (4 loads), leaves {T+2,T+3} = 8 in flight.
// Phases: ph0 {8 ds_read, stage A(T+3), bar, lgkm0, 16 MFMA (mi0-3), bar}
//         ph1 {4 ds_read, stage B(T+3), bar, lgkm0, 16 MFMA (mi4-7), vmcnt(8), bar}
// XCD-band mapping (nbm == 32 == 8 XCDs x 4 rows): xcd owns 4 bm rows,
// column-major within band -> concurrent blocks share A panels in L2.
template <bool BF16OUT>
__global__ __launch_bounds__(512, 2) void gemm256(const u16* __restrict__ A,
                                                  const u16* __restrict__ B,
                                                  const float* __restrict__ bias,
                                                  float* __restrict__ outF,
                                                  u16* __restrict__ outB,
                                                  int N, int K) {
  __shared__ __align__(16) u16 As[4][8192];
  __shared__ __align__(16) u16 Bs[4][8192];
  const int tid = threadIdx.x;
  const int w = tid >> 6, l = tid & 63;
  const int wm = w >> 2, wn = w & 3;
  const int fr = l & 15, g = l >> 4;
  // XCD-band mapping (assumes hardware round-robin bid->XCD = bid%8)
  const int xcd = blockIdx.x & 7, loc = blockIdx.x >> 3;
  const int bn = loc >> 2, bm = xcd * 4 + (loc & 3);

  const u16* Ab = A + (size_t)bm * 256 * K;
  const u16* Bb = B + (size_t)bn * 256 * K;

  // staging: thread writes slot bytes h*8192 + w*1024 + l*16
  //   -> row = h*128 + w*16 + (l>>2), phys 16B-chunk = l&3
  //   logical chunk = phys ^ ((row>>1)&3) = (l&3) ^ ((l>>3)&3)
  const int r_st = w * 16 + (l >> 2);
  const int s_st = ((l & 3) ^ ((l >> 3) & 3)) * 8;
  // fragment read: row = *+fr, phys chunk = g ^ ((fr>>1)&3)
  const int sw = (g ^ ((fr >> 1) & 3)) * 8;

  f32x4 acc[8][4];
#pragma unroll
  for (int i = 0; i < 8; ++i)
#pragma unroll
    for (int j = 0; j < 4; ++j) acc[i][j] = (f32x4){0.f, 0.f, 0.f, 0.f};

  auto stA = [&](int T) {
    const int s = T & 3;
#pragma unroll
    for (int h = 0; h < 2; ++h)
      gload_lds16(Ab + (size_t)(h * 128 + r_st) * K + T * 32 + s_st,
                  (char*)&As[s][0] + h * 8192 + w * 1024 + l * 16);
  };
  auto stB = [&](int T) {
    const int s = T & 3;
#pragma unroll
    for (int h = 0; h < 2; ++h)
      gload_lds16(Bb + (size_t)(h * 128 + r_st) * K + T * 32 + s_st,
                  (char*)&Bs[s][0] + h * 8192 + w * 1024 + l * 16);
  };

  // prologue: stage subtiles 0,1,2 (12 loads); drain oldest 4 -> subtile 0 ready
  stA(0); stB(0); stA(1); stB(1); stA(2); stB(2);
  asm volatile("s_waitcnt vmcnt(8)" ::: "memory");
  __builtin_amdgcn_s_barrier();
  __builtin_amdgcn_sched_barrier(0);

  const int NT = K >> 5;

  auto step = [&](int T, bool doStage, int vm) {
    const u16* as_ = &As[T & 3][0] + (wm * 128 + fr) * 32 + sw;
    const u16* bs_ = &Bs[T & 3][0] + (wn * 64 + fr) * 32 + sw;
    bf16x8 af[8], bf[4];
    // ---- ph0 ----
#pragma unroll
    for (int mi = 0; mi < 4; ++mi) af[mi] = *(const bf16x8*)(as_ + mi * 512);
#pragma unroll
    for (int ni = 0; ni < 4; ++ni) bf[ni] = *(const bf16x8*)(bs_ + ni * 512);
    if (doStage) stA(T + 3);
    __builtin_amdgcn_s_barrier();
    asm volatile("s_waitcnt lgkmcnt(0)" ::: "memory");
    __builtin_amdgcn_s_setprio(1);
#pragma unroll
    for (int mi = 0; mi < 4; ++mi)
#pragma unroll
      for (int ni = 0; ni < 4; ++ni)
        acc[mi][ni] = __builtin_amdgcn_mfma_f32_16x16x32_bf16(af[mi], bf[ni], acc[mi][ni], 0, 0, 0);
    __builtin_amdgcn_s_setprio(0);
    __builtin_amdgcn_s_barrier();
    // ---- ph1 ----
#pragma unroll
    for (int mi = 4; mi < 8; ++mi) af[mi] = *(const bf16x8*)(as_ + mi * 512);
    if (doStage) stB(T + 3);
    __builtin_amdgcn_s_barrier();
    asm volatile("s_waitcnt lgkmcnt(0)" ::: "memory");
    __builtin_amdgcn_s_setprio(1);
#pragma unroll
    for (int mi = 4; mi < 8; ++mi)
#pragma unroll
      for (int ni = 0; ni < 4; ++ni)
        acc[mi][ni] = __builtin_amdgcn_mfma_f32_16x16x32_bf16(af[mi], bf[ni], acc[mi][ni], 0, 0, 0);
    __builtin_amdgcn_s_setprio(0);
    if (vm == 8) asm volatile("s_waitcnt vmcnt(8)" ::: "memory");
    else if (vm == 4) asm volatile("s_waitcnt vmcnt(4)" ::: "memory");
    else if (vm == 0) asm volatile("s_waitcnt vmcnt(0)" ::: "memory");
    __builtin_amdgcn_s_barrier();
    __builtin_amdgcn_sched_barrier(0);
  };

  for (int T = 0; T < NT - 3; ++T) step(T, true, 8);
  step(NT - 3, false, 4);
  step(NT - 2, false, 0);
  step(NT - 1, false, -1);

  // epilogue
#pragma unroll
  for (int ni = 0; ni < 4; ++ni) {
    const int c = bn * 256 + wn * 64 + ni * 16 + fr;
    const float bvv = bias ? bias[c] : 0.0f;
#pragma unroll
    for (int mi = 0; mi < 8; ++mi) {
      const int r0 = bm * 256 + wm * 128 + mi * 16 + g * 4;
#pragma unroll
      for (int jj = 0; jj < 4; ++jj) {
        float v = acc[mi][ni][jj] + bvv;
        if (BF16OUT) outB[(size_t)(r0 + jj) * N + c] = f2b(v);
        else         outF[(size_t)(r0 + jj) * N + c] = v;
      }
    }
  }
}

// ---------------- V transpose: Vt[3072][8192] <- QKV[:, 6144+c] ----------------
__global__ __launch_bounds__(256) void vtrans(const u16* __restrict__ QKV,
                                              u16* __restrict__ Vt) {
  __shared__ u16 t[64][72];
  const int tid = threadIdx.x;
  const int s0 = blockIdx.x * 64, c0 = blockIdx.y * 64;
  {
    const int r2 = tid >> 3, cc = (tid & 7) * 8;
#pragma unroll
    for (int p = 0; p < 2; ++p) {
      const int row = r2 + p * 32;
      u16 tmp[8];
      *(uint4*)tmp = *(const uint4*)(QKV + (size_t)(s0 + row) * QKVN + 2 * HDIM + c0 + cc);
#pragma unroll
      for (int j = 0; j < 8; ++j) t[row][cc + j] = tmp[j];
    }
  }
  __syncthreads();
  {
    const int cr2 = tid >> 3, sc = tid & 7;
#pragma unroll
    for (int p = 0; p < 2; ++p) {
      const int c = cr2 + p * 32;
      u16 tmp[8];
#pragma unroll
      for (int j = 0; j < 8; ++j) tmp[j] = t[sc * 8 + j][c];
      *(uint4*)(Vt + (size_t)(c0 + c) * SEQ + s0 + sc * 8) = *(uint4*)tmp;
    }
  }
}

// ---------------- windowed flash attention ----------------
// grid (8 qb, 12 h, 19 win), 4 waves. Each wave: 16 q-rows, online softmax over 8 chunks of 64 kv.
__global__ __launch_bounds__(256, 2) void attn_kernel(const u16* __restrict__ QKV,
                                                      const u16* __restrict__ Vt,
                                                      u16* __restrict__ ctxw) {
  __shared__ __align__(16) u16 Ks[64 * 256];   // [kv][d], chunk-swizzled (XOR row&31 on 16B chunks)
  __shared__ __align__(16) u16 Vts[256 * 64];  // [d][kv], chunk-swizzled (XOR row&7)
  __shared__ __align__(16) u16 Ps[4][16 * 64]; // per-wave P scratch, XOR (q&7)<<4 byte swizzle
  const int qb = blockIdx.x, h = blockIdx.y, n = blockIdx.z;
  const int tid = threadIdx.x, w = tid >> 6, l = tid & 63;
  const int g = l >> 4, fr = l & 15;
  const int s0 = n * STR;

  // Q fragments (16 rows per wave) straight from global
  bf16x8 qf[8];
  {
    int sq = s0 + qb * 64 + w * 16 + fr;
    if (sq > SEQ - 1) sq = SEQ - 1;
    const u16* qbase = QKV + (size_t)sq * QKVN + h * DHEAD + g * 8;
#pragma unroll
    for (int dc = 0; dc < 8; ++dc) qf[dc] = *(const bf16x8*)(qbase + dc * 32);
  }
  f32x4 ctx[16];
#pragma unroll
  for (int dn = 0; dn < 16; ++dn) ctx[dn] = (f32x4){0.f, 0.f, 0.f, 0.f};
  float mrow[4] = {-3e38f, -3e38f, -3e38f, -3e38f};
  float lrow[4] = {0.f, 0.f, 0.f, 0.f};

  const int kr_in = l >> 5;  // K staging: row within 2-row chunk
  const int kcp = l & 31;    // K staging: physical 16B chunk in row
  const int vr_in = l >> 3;  // V staging: row within 8-row chunk
  const int vcp = l & 7;

  for (int kt = 0; kt < 8; ++kt) {
    const int sb = s0 + kt * 64;
    // ---- stage K[64][256] and Vt-slice[256][64], source pre-swizzled ----
#pragma unroll
    for (int i = 0; i < 8; ++i) {
      const int c = i * 4 + w;  // 1KB chunk id, 0..31
      {
        const int krow = c * 2 + kr_in;
        const int cl = kcp ^ (krow & 31);
        int sk = sb + krow;
        if (sk > SEQ - 1) sk = SEQ - 1;
        gload_lds16(QKV + (size_t)sk * QKVN + HDIM + h * DHEAD + cl * 8, (char*)Ks + c * 1024);
      }
      {
        const int d = c * 8 + vr_in;
        const int cl = vcp ^ (d & 7);
        int sv = sb + cl * 8;
        if (sv > SEQ - 8) sv = SEQ - 8;
        gload_lds16(Vt + (size_t)(h * DHEAD + d) * SEQ + sv, (char*)Vts + c * 1024);
      }
    }
    __syncthreads();

    // ---- S = Q K^T (rows q=(g*4+r), cols kv=kn*16+fr) ----
    f32x4 sacc[4];
#pragma unroll
    for (int kn = 0; kn < 4; ++kn) sacc[kn] = (f32x4){0.f, 0.f, 0.f, 0.f};
#pragma unroll
    for (int kn = 0; kn < 4; ++kn) {
      const int krow = kn * 16 + fr;
      const char* krp = (const char*)Ks + krow * 512;
      const int rx = krow & 31;
#pragma unroll
      for (int dc = 0; dc < 8; ++dc) {
        bf16x8 kf = *(const bf16x8*)(krp + (((dc * 4 + g) ^ rx) << 4));
        sacc[kn] = __builtin_amdgcn_mfma_f32_16x16x32_bf16(qf[dc], kf, sacc[kn], 0, 0, 0);
      }
    }
    // ---- scale + validity mask + online softmax ----
    float mt[4];
#pragma unroll
    for (int kn = 0; kn < 4; ++kn) {
      const bool valid = (sb + kn * 16 + fr) < SEQ;
#pragma unroll
      for (int r = 0; r < 4; ++r) {
        float v = valid ? sacc[kn][r] * ATTN_SCALE : -1e9f;
        sacc[kn][r] = v;
        mt[r] = (kn == 0) ? v : fmaxf(mt[r], v);
      }
    }
#pragma unroll
    for (int r = 0; r < 4; ++r) {
#pragma unroll
      for (int off = 1; off < 16; off <<= 1)
        mt[r] = fmaxf(mt[r], __shfl_xor(mt[r], off, 64));
    }
    float corr[4];
#pragma unroll
    for (int r = 0; r < 4; ++r) {
      float mnew = fmaxf(mrow[r], mt[r]);
      corr[r] = __expf(mrow[r] - mnew);
      mrow[r] = mnew;
    }
    float psum[4] = {0.f, 0.f, 0.f, 0.f};
    char* pw = (char*)&Ps[w][0];
#pragma unroll
    for (int kn = 0; kn < 4; ++kn) {
#pragma unroll
      for (int r = 0; r < 4; ++r) {
        float p = __expf(sacc[kn][r] - mrow[r]);
        psum[r] += p;
        const int q = g * 4 + r;
        *(u16*)(pw + q * 128 + ((2 * (kn * 16 + fr)) ^ ((q & 7) << 4))) = f2b(p);
      }
    }
#pragma unroll
    for (int r = 0; r < 4; ++r) {
#pragma unroll
      for (int off = 1; off < 16; off <<= 1)
        psum[r] += __shfl_xor(psum[r], off, 64);
      lrow[r] = lrow[r] * corr[r] + psum[r];
    }
#pragma unroll
    for (int dn = 0; dn < 16; ++dn)
#pragma unroll
      for (int r = 0; r < 4; ++r) ctx[dn][r] *= corr[r];
    __syncthreads();  // Ps visible (and ordered) before fragment reads

    // ---- ctx += P * V (via Vt rows as B^T) ----
    bf16x8 pf[2];
#pragma unroll
    for (int kc = 0; kc < 2; ++kc)
      pf[kc] = *(const bf16x8*)(pw + fr * 128 + ((kc * 64 + g * 16) ^ ((fr & 7) << 4)));
#pragma unroll
    for (int dn = 0; dn < 16; ++dn) {
      const int d = dn * 16 + fr;
      const char* vrp = (const char*)Vts + d * 128;
      const int dx = d & 7;
#pragma unroll
      for (int kc = 0; kc < 2; ++kc) {
        bf16x8 vf = *(const bf16x8*)(vrp + (((kc * 4 + g) ^ dx) << 4));
        ctx[dn] = __builtin_amdgcn_mfma_f32_16x16x32_bf16(pf[kc], vf, ctx[dn], 0, 0, 0);
      }
    }
    __syncthreads();  // all waves done with Ks/Vts before next stage
  }
  // ---- epilogue: normalize and store ctx ----
  float inv[4];
#pragma unroll
  for (int r = 0; r < 4; ++r) inv[r] = 1.0f / lrow[r];
  const int qrow0 = qb * 64 + w * 16 + g * 4;
#pragma unroll
  for (int dn = 0; dn < 16; ++dn) {
#pragma unroll
    for (int r = 0; r < 4; ++r) {
      ctxw[(size_t)(n * WINL + qrow0 + r) * HDIM + h * DHEAD + dn * 16 + fr] =
          f2b(ctx[dn][r] * inv[r]);
    }
  }
}

// ---------------- overlap-average combine: ctx_avg[8192][3072] ----------------
__global__ __launch_bounds__(256) void combine_kernel(const u16* __restrict__ ctxw,
                                                      u16* __restrict__ ctx_avg) {
  int idx = blockIdx.x * 256 + threadIdx.x;
  if (idx >= SEQ * (HDIM / 8)) return;
  const int s = idx / (HDIM / 8);
  const int cc = (idx % (HDIM / 8)) * 8;
  const int w1 = s / STR;          // <= 18
  const int off1 = s - w1 * STR;   // 0..447
  us8 a = *(const us8*)(ctxw + (size_t)(w1 * WINL + off1) * HDIM + cc);
  if (w1 >= 1 && off1 < (WINL - STR)) {
    us8 b = *(const us8*)(ctxw + (size_t)((w1 - 1) * WINL + off1 + STR) * HDIM + cc);
#pragma unroll
    for (int j = 0; j < 8; ++j) a[j] = f2b(0.5f * (b2f(a[j]) + b2f(b[j])));
  }
  *(us8*)(ctx_avg + (size_t)s * HDIM + cc) = a;
}

__global__ void ws_marker(float* out, float v) { out[0] = v; }

// ---------------- launch ----------------
extern "C" void kernel_launch(void* const* d_in, const int* in_sizes, int n_in,
                              void* d_out, int out_size, void* d_ws, size_t ws_size,
                              hipStream_t stream) {
  const float* X  = (const float*)d_in[0];
  const float* Wq = (const float*)d_in[1];
  const float* bq = (const float*)d_in[2];
  const float* Wk = (const float*)d_in[3];
  const float* bk = (const float*)d_in[4];
  const float* Wv = (const float*)d_in[5];
  const float* bv = (const float*)d_in[6];
  const float* Wo = (const float*)d_in[7];
  const float* bo = (const float*)d_in[8];
  float* out = (float*)d_out;

  // workspace layout (bytes)
  const size_t OFF_XB   = 0;                          // 8192*3072*2   = 50331648
  const size_t OFF_WQKV = 50331648;                   // 9216*3072*2   = 56623104
  const size_t OFF_WO   = 106954752;                  // 3072*3072*2   = 18874368
  const size_t OFF_QKV  = 125829120;                  // 8192*9216*2   = 150994944
  const size_t OFF_VT   = 276824064;                  // 3072*8192*2   = 50331648
  const size_t OFF_BIAS = 327155712;                  // 9216*4        = 36864
  const size_t WS_NEED  = 327192576;
  if (ws_size < WS_NEED) {
    hipMemsetAsync(d_out, 0, (size_t)out_size * 4, stream);
    ws_marker<<<1, 1, 0, stream>>>(out, (float)(ws_size / 1048576));
    return;
  }
  char* ws = (char*)d_ws;
  u16* Xb      = (u16*)(ws + OFF_XB);
  u16* Wqkvb   = (u16*)(ws + OFF_WQKV);
  u16* Wob     = (u16*)(ws + OFF_WO);
  u16* QKV     = (u16*)(ws + OFF_QKV);
  u16* Vt      = (u16*)(ws + OFF_VT);
  float* biasQ = (float*)(ws + OFF_BIAS);
  u16* ctxw    = (u16*)d_out;  // 59.8MB scratch inside the 100.7MB output buffer
  u16* ctx_avg = Xb;           // alias: Xb dead after QKV GEMM

  cvt_f32_bf16<<<12288, 256, 0, stream>>>(X, Xb, SEQ * HDIM / 8);
  cvt_f32_bf16<<<4608, 256, 0, stream>>>(Wq, Wqkvb, HDIM * HDIM / 8);
  cvt_f32_bf16<<<4608, 256, 0, stream>>>(Wk, Wqkvb + (size_t)HDIM * HDIM, HDIM * HDIM / 8);
  cvt_f32_bf16<<<4608, 256, 0, stream>>>(Wv, Wqkvb + (size_t)2 * HDIM * HDIM, HDIM * HDIM / 8);
  cvt_f32_bf16<<<4608, 256, 0, stream>>>(Wo, Wob, HDIM * HDIM / 8);
  biascat<<<36, 256, 0, stream>>>(bq, bk, bv, biasQ);

  gemm256<true><<<dim3((SEQ / 256) * (QKVN / 256)), 512, 0, stream>>>(
      Xb, Wqkvb, biasQ, nullptr, QKV, QKVN, HDIM);

  vtrans<<<dim3(SEQ / 64, HDIM / 64), 256, 0, stream>>>(QKV, Vt);

  attn_kernel<<<dim3(8, NHEAD, NWIN), 256, 0, stream>>>(QKV, Vt, ctxw);

  combine_kernel<<<12288, 256, 0, stream>>>(ctxw, ctx_avg);

  gemm256<false><<<dim3((SEQ / 256) * (HDIM / 256)), 512, 0, stream>>>(
      ctx_avg, Wob, bo, out, nullptr, HDIM, HDIM);
}

// Round 4
// 858.780 us; speedup vs baseline: 1.2597x; 1.1077x over previous
//
#include <hip/hip_runtime.h>
#include <hip/hip_bf16.h>
#include <stdint.h>

// Problem constants
#define SEQ   8192
#define HDIM  3072
#define NWIN  19
#define WINL  512
#define STR   448
#define NHEAD 12
#define DHEAD 256
#define QKVN  9216
#define ATTN_SCALE 0.0625f

typedef unsigned short u16;
typedef __bf16 bf16x8 __attribute__((ext_vector_type(8)));
typedef float  f32x4  __attribute__((ext_vector_type(4)));
typedef unsigned short us8 __attribute__((ext_vector_type(8)));

__device__ __forceinline__ u16 f2b(float x) {
  return __builtin_bit_cast(u16, __float2bfloat16(x));
}
__device__ __forceinline__ float b2f(u16 u) {
  return __builtin_bit_cast(float, (unsigned int)(u) << 16);
}
__device__ __forceinline__ void gload_lds16(const void* g, void* l) {
  __builtin_amdgcn_global_load_lds(
      (const __attribute__((address_space(1))) void*)g,
      (__attribute__((address_space(3))) void*)l, 16, 0, 0);
}

// ---------------- elementwise converts ----------------
__global__ __launch_bounds__(256) void cvt_f32_bf16(const float* __restrict__ src,
                                                    u16* __restrict__ dst, int n8) {
  int i = blockIdx.x * 256 + threadIdx.x;
  if (i >= n8) return;
  const float4* s4 = (const float4*)src;
  float4 a = s4[2 * i], b = s4[2 * i + 1];
  us8 o;
  o[0] = f2b(a.x); o[1] = f2b(a.y); o[2] = f2b(a.z); o[3] = f2b(a.w);
  o[4] = f2b(b.x); o[5] = f2b(b.y); o[6] = f2b(b.z); o[7] = f2b(b.w);
  *((us8*)dst + i) = o;
}

__global__ __launch_bounds__(256) void biascat(const float* __restrict__ bq,
                                               const float* __restrict__ bk,
                                               const float* __restrict__ bv,
                                               float* __restrict__ dst) {
  int i = blockIdx.x * 256 + threadIdx.x;
  if (i >= QKVN) return;
  dst[i] = (i < HDIM) ? bq[i] : ((i < 2 * HDIM) ? bk[i - HDIM] : bv[i - 2 * HDIM]);
}

// ---------------- 256x256 8-phase GEMM: C = A * B^T (+bias) ----------------
// A[M][K] bf16 row-major, B[N][K] bf16 row-major. K-tile BK=64.
// 8 waves (2Mx4N). Interleaved ownership: wave (wm,wn) computes
//   C rows  mi*32 + wm*16 + {0..15}, mi=0..7  (mi0-3 in A-lo half, mi4-7 A-hi)
//   C cols  ni*64 + wn*16 + {0..15}, ni=0..3  (ni0-1 in B-lo half, ni2-3 B-hi)
// LDS: [2 dbuf][2 half][128][64] per operand = 128 KiB total.
// Col storage 16B-chunk-swizzled: phys_chunk = logical_chunk ^ (row&7)
//   (staging source pre-swizzled; read addr swizzled; involution both sides).
// Phases per K-tile T (compute from buf[T&1], stage T+1 into buf[(T+1)&1]):
//   P0: rd af(mi0-3,kk01)=8 + bf(ni0-1)=4; stage Alo(T+1); bar; lgkm0;
//       16 MFMA (mi0-3 x ni0-1 x kk01); vmcnt(4); bar
//   P1: rd bf(ni2-3)=4; stage Blo(T+1); bar; lgkm0; 16 MFMA (mi0-3 x ni2-3);
//       vmcnt(4); bar
//   P2: rd af(mi4-7)=8; stage Bhi(T+1); bar; lgkm0; 16 MFMA (mi4-7 x ni0-1); bar
//   P3: stage Ahi(T+1); bar; 16 MFMA (mi4-7 x ni2-3); vmcnt(4); bar
// vmcnt liveness (steady state, 2 gloads per half, issue order per tile
// Alo,Blo,Bhi,Ahi):
//   end P3(T): outstanding {Alo,Blo,Bhi,Ahi}(T+1)=8 -> vmcnt(4) completes
//     Alo,Blo(T+1), needed by P0(T+1).
//   end P0(T): outstanding {Bhi,Ahi}(T)+Alo(T+1)... (shifted one tile) ->
//     vmcnt(4) completes Bhi(T+1-cycle) needed by P1's bf-hi reads.
//   end P1(T): vmcnt(4) completes Ahi needed by P2's af-hi reads.
//   Last tile: P0 vmcnt(2), P1 vmcnt(0) (epilogue drain; nothing new staged).
// LDS write-after-read: half staged at phase p of T was last ds_read >=2
// barriers earlier in tile T-1 (same parity) -> race-free.
template <bool BF16OUT>
__global__ __launch_bounds__(512, 2) void gemm256(const u16* __restrict__ A,
                                                  const u16* __restrict__ B,
                                                  const float* __restrict__ bias,
                                                  float* __restrict__ outF,
                                                  u16* __restrict__ outB,
                                                  int N, int K) {
  __shared__ __align__(16) u16 As[2][2][128][64];
  __shared__ __align__(16) u16 Bs[2][2][128][64];
  const int tid = threadIdx.x;
  const int w = tid >> 6, l = tid & 63;
  const int wm = w >> 2, wn = w & 3;
  const int fr = l & 15, g = l >> 4;
  // XCD-band mapping (assumes hardware round-robin bid->XCD = bid%8);
  // nbm = M/256 = 32 = 8 XCDs x 4 rows for both GEMMs.
  const int xcd = blockIdx.x & 7, loc = blockIdx.x >> 3;
  const int bn = loc >> 2, bm = xcd * 4 + (loc & 3);

  // Staging: thread t writes half bytes t*16 and 8192+t*16
  //  -> rows t>>3 and 64+(t>>3), phys chunk t&7;
  //  inverse-swizzled source col chunk = (t&7) ^ ((t>>3)&7) (row&7 == (t>>3)&7).
  const int srow = tid >> 3;
  const int lc = (tid & 7) ^ ((tid >> 3) & 7);
  const u16* sA0 = A + (size_t)(bm * 256 + srow) * K + lc * 8;
  const u16* sA1 = sA0 + (size_t)64 * K;
  const u16* sB0 = B + (size_t)(bn * 256 + srow) * K + lc * 8;
  const u16* sB1 = sB0 + (size_t)64 * K;
  const size_t hiK = (size_t)128 * K;
  const int t16 = tid * 16;
  char* Aw = (char*)As;
  char* Bw = (char*)Bs;

  // Fragment read offsets (bytes within a [128][64] half):
  //  A row (in half) = mi*32 + wm*16 + fr ; B row = (ni&1)*64 + wn*16 + fr
  //  chunk = (kk*4+g) ^ (row&7), row&7 == fr&7 for all frags.
  int rbA[4], rbB[2], ck[2];
#pragma unroll
  for (int i = 0; i < 4; ++i) rbA[i] = (i * 32 + wm * 16 + fr) * 128;
  rbB[0] = (wn * 16 + fr) * 128;
  rbB[1] = (64 + wn * 16 + fr) * 128;
  ck[0] = ((g) ^ (fr & 7)) * 16;
  ck[1] = ((4 + g) ^ (fr & 7)) * 16;

  f32x4 acc[8][4];
#pragma unroll
  for (int i = 0; i < 8; ++i)
#pragma unroll
    for (int j = 0; j < 4; ++j) acc[i][j] = (f32x4){0.f, 0.f, 0.f, 0.f};

  // prologue: stage tile0 (Alo,Blo,Bhi,Ahi) into parity 0
  gload_lds16(sA0, Aw + t16); gload_lds16(sA1, Aw + 8192 + t16);
  gload_lds16(sB0, Bw + t16); gload_lds16(sB1, Bw + 8192 + t16);
  gload_lds16(sB0 + hiK, Bw + 16384 + t16); gload_lds16(sB1 + hiK, Bw + 16384 + 8192 + t16);
  gload_lds16(sA0 + hiK, Aw + 16384 + t16); gload_lds16(sA1 + hiK, Aw + 16384 + 8192 + t16);
  sA0 += 64; sA1 += 64; sB0 += 64; sB1 += 64;  // -> tile 1
  asm volatile("s_waitcnt vmcnt(4)" ::: "memory");
  __builtin_amdgcn_s_barrier();
  __builtin_amdgcn_sched_barrier(0);

  const int NT = K >> 6;
  for (int T = 0; T < NT; ++T) {
    const int cur = T & 1, pp = (T + 1) & 1;
    const bool ds = (T + 1 < NT);
    const bool last = (T == NT - 1);
    const char* ah = (const char*)As + cur * 32768;
    const char* bh = (const char*)Bs + cur * 32768;
    char* apw = Aw + pp * 32768;
    char* bpw = Bw + pp * 32768;
    bf16x8 af[4][2], bf[4][2];

    // ---------------- P0 ----------------
#pragma unroll
    for (int mi = 0; mi < 4; ++mi)
#pragma unroll
      for (int kk = 0; kk < 2; ++kk)
        af[mi][kk] = *(const bf16x8*)(ah + rbA[mi] + ck[kk]);
#pragma unroll
    for (int ni = 0; ni < 2; ++ni)
#pragma unroll
      for (int kk = 0; kk < 2; ++kk)
        bf[ni][kk] = *(const bf16x8*)(bh + rbB[ni] + ck[kk]);
    if (ds) { gload_lds16(sA0, apw + t16); gload_lds16(sA1, apw + 8192 + t16); }
    __builtin_amdgcn_s_barrier();
    asm volatile("s_waitcnt lgkmcnt(0)" ::: "memory");
    __builtin_amdgcn_s_setprio(1);
#pragma unroll
    for (int kk = 0; kk < 2; ++kk)
#pragma unroll
      for (int mi = 0; mi < 4; ++mi)
#pragma unroll
        for (int ni = 0; ni < 2; ++ni)
          acc[mi][ni] = __builtin_amdgcn_mfma_f32_16x16x32_bf16(af[mi][kk], bf[ni][kk], acc[mi][ni], 0, 0, 0);
    __builtin_amdgcn_s_setprio(0);
    if (last) asm volatile("s_waitcnt vmcnt(2)" ::: "memory");
    else      asm volatile("s_waitcnt vmcnt(4)" ::: "memory");
    __builtin_amdgcn_s_barrier();

    // ---------------- P1 ----------------
#pragma unroll
    for (int ni = 2; ni < 4; ++ni)
#pragma unroll
      for (int kk = 0; kk < 2; ++kk)
        bf[ni][kk] = *(const bf16x8*)(bh + 16384 + rbB[ni - 2] + ck[kk]);
    if (ds) { gload_lds16(sB0, bpw + t16); gload_lds16(sB1, bpw + 8192 + t16); }
    __builtin_amdgcn_s_barrier();
    asm volatile("s_waitcnt lgkmcnt(0)" ::: "memory");
    __builtin_amdgcn_s_setprio(1);
#pragma unroll
    for (int kk = 0; kk < 2; ++kk)
#pragma unroll
      for (int mi = 0; mi < 4; ++mi)
#pragma unroll
        for (int ni = 2; ni < 4; ++ni)
          acc[mi][ni] = __builtin_amdgcn_mfma_f32_16x16x32_bf16(af[mi][kk], bf[ni][kk], acc[mi][ni], 0, 0, 0);
    __builtin_amdgcn_s_setprio(0);
    if (last) asm volatile("s_waitcnt vmcnt(0)" ::: "memory");
    else      asm volatile("s_waitcnt vmcnt(4)" ::: "memory");
    __builtin_amdgcn_s_barrier();

    // ---------------- P2 ----------------
#pragma unroll
    for (int mi = 0; mi < 4; ++mi)
#pragma unroll
      for (int kk = 0; kk < 2; ++kk)
        af[mi][kk] = *(const bf16x8*)(ah + 16384 + rbA[mi] + ck[kk]);
    if (ds) { gload_lds16(sB0 + hiK, bpw + 16384 + t16); gload_lds16(sB1 + hiK, bpw + 16384 + 8192 + t16); }
    __builtin_amdgcn_s_barrier();
    asm volatile("s_waitcnt lgkmcnt(0)" ::: "memory");
    __builtin_amdgcn_s_setprio(1);
#pragma unroll
    for (int kk = 0; kk < 2; ++kk)
#pragma unroll
      for (int mi = 0; mi < 4; ++mi)
#pragma unroll
        for (int ni = 0; ni < 2; ++ni)
          acc[mi + 4][ni] = __builtin_amdgcn_mfma_f32_16x16x32_bf16(af[mi][kk], bf[ni][kk], acc[mi + 4][ni], 0, 0, 0);
    __builtin_amdgcn_s_setprio(0);
    __builtin_amdgcn_s_barrier();

    // ---------------- P3 ----------------
    if (ds) { gload_lds16(sA0 + hiK, apw + 16384 + t16); gload_lds16(sA1 + hiK, apw + 16384 + 8192 + t16); }
    __builtin_amdgcn_s_barrier();
    __builtin_amdgcn_s_setprio(1);
#pragma unroll
    for (int kk = 0; kk < 2; ++kk)
#pragma unroll
      for (int mi = 0; mi < 4; ++mi)
#pragma unroll
        for (int ni = 2; ni < 4; ++ni)
          acc[mi + 4][ni] = __builtin_amdgcn_mfma_f32_16x16x32_bf16(af[mi][kk], bf[ni][kk], acc[mi + 4][ni], 0, 0, 0);
    __builtin_amdgcn_s_setprio(0);
    if (!last) asm volatile("s_waitcnt vmcnt(4)" ::: "memory");
    __builtin_amdgcn_s_barrier();
    if (ds) { sA0 += 64; sA1 += 64; sB0 += 64; sB1 += 64; }
    __builtin_amdgcn_sched_barrier(0);
  }

  // epilogue
#pragma unroll
  for (int ni = 0; ni < 4; ++ni) {
    const int c = bn * 256 + ni * 64 + wn * 16 + fr;
    const float bvv = bias ? bias[c] : 0.0f;
#pragma unroll
    for (int mi = 0; mi < 8; ++mi) {
      const int r0 = bm * 256 + mi * 32 + wm * 16 + g * 4;
#pragma unroll
      for (int jj = 0; jj < 4; ++jj) {
        float v = acc[mi][ni][jj] + bvv;
        if (BF16OUT) outB[(size_t)(r0 + jj) * N + c] = f2b(v);
        else         outF[(size_t)(r0 + jj) * N + c] = v;
      }
    }
  }
}

// ---------------- V transpose: Vt[3072][8192] <- QKV[:, 6144+c] ----------------
__global__ __launch_bounds__(256) void vtrans(const u16* __restrict__ QKV,
                                              u16* __restrict__ Vt) {
  __shared__ u16 t[64][72];
  const int tid = threadIdx.x;
  const int s0 = blockIdx.x * 64, c0 = blockIdx.y * 64;
  {
    const int r2 = tid >> 3, cc = (tid & 7) * 8;
#pragma unroll
    for (int p = 0; p < 2; ++p) {
      const int row = r2 + p * 32;
      u16 tmp[8];
      *(uint4*)tmp = *(const uint4*)(QKV + (size_t)(s0 + row) * QKVN + 2 * HDIM + c0 + cc);
#pragma unroll
      for (int j = 0; j < 8; ++j) t[row][cc + j] = tmp[j];
    }
  }
  __syncthreads();
  {
    const int cr2 = tid >> 3, sc = tid & 7;
#pragma unroll
    for (int p = 0; p < 2; ++p) {
      const int c = cr2 + p * 32;
      u16 tmp[8];
#pragma unroll
      for (int j = 0; j < 8; ++j) tmp[j] = t[sc * 8 + j][c];
      *(uint4*)(Vt + (size_t)(c0 + c) * SEQ + s0 + sc * 8) = *(uint4*)tmp;
    }
  }
}

// ---------------- windowed flash attention ----------------
// grid (8 qb, 12 h, 19 win), 4 waves. Each wave: 16 q-rows, online softmax over 8 chunks of 64 kv.
__global__ __launch_bounds__(256, 2) void attn_kernel(const u16* __restrict__ QKV,
                                                      const u16* __restrict__ Vt,
                                                      u16* __restrict__ ctxw) {
  __shared__ __align__(16) u16 Ks[64 * 256];   // [kv][d], chunk-swizzled (XOR row&31 on 16B chunks)
  __shared__ __align__(16) u16 Vts[256 * 64];  // [d][kv], chunk-swizzled (XOR row&7)
  __shared__ __align__(16) u16 Ps[4][16 * 64]; // per-wave P scratch, XOR (q&7)<<4 byte swizzle
  const int qb = blockIdx.x, h = blockIdx.y, n = blockIdx.z;
  const int tid = threadIdx.x, w = tid >> 6, l = tid & 63;
  const int g = l >> 4, fr = l & 15;
  const int s0 = n * STR;

  // Q fragments (16 rows per wave) straight from global
  bf16x8 qf[8];
  {
    int sq = s0 + qb * 64 + w * 16 + fr;
    if (sq > SEQ - 1) sq = SEQ - 1;
    const u16* qbase = QKV + (size_t)sq * QKVN + h * DHEAD + g * 8;
#pragma unroll
    for (int dc = 0; dc < 8; ++dc) qf[dc] = *(const bf16x8*)(qbase + dc * 32);
  }
  f32x4 ctx[16];
#pragma unroll
  for (int dn = 0; dn < 16; ++dn) ctx[dn] = (f32x4){0.f, 0.f, 0.f, 0.f};
  float mrow[4] = {-3e38f, -3e38f, -3e38f, -3e38f};
  float lrow[4] = {0.f, 0.f, 0.f, 0.f};

  const int kr_in = l >> 5;  // K staging: row within 2-row chunk
  const int kcp = l & 31;    // K staging: physical 16B chunk in row
  const int vr_in = l >> 3;  // V staging: row within 8-row chunk
  const int vcp = l & 7;

  for (int kt = 0; kt < 8; ++kt) {
    const int sb = s0 + kt * 64;
    // ---- stage K[64][256] and Vt-slice[256][64], source pre-swizzled ----
#pragma unroll
    for (int i = 0; i < 8; ++i) {
      const int c = i * 4 + w;  // 1KB chunk id, 0..31
      {
        const int krow = c * 2 + kr_in;
        const int cl = kcp ^ (krow & 31);
        int sk = sb + krow;
        if (sk > SEQ - 1) sk = SEQ - 1;
        gload_lds16(QKV + (size_t)sk * QKVN + HDIM + h * DHEAD + cl * 8, (char*)Ks + c * 1024);
      }
      {
        const int d = c * 8 + vr_in;
        const int cl = vcp ^ (d & 7);
        int sv = sb + cl * 8;
        if (sv > SEQ - 8) sv = SEQ - 8;
        gload_lds16(Vt + (size_t)(h * DHEAD + d) * SEQ + sv, (char*)Vts + c * 1024);
      }
    }
    __syncthreads();

    // ---- S = Q K^T (rows q=(g*4+r), cols kv=kn*16+fr) ----
    f32x4 sacc[4];
#pragma unroll
    for (int kn = 0; kn < 4; ++kn) sacc[kn] = (f32x4){0.f, 0.f, 0.f, 0.f};
#pragma unroll
    for (int kn = 0; kn < 4; ++kn) {
      const int krow = kn * 16 + fr;
      const char* krp = (const char*)Ks + krow * 512;
      const int rx = krow & 31;
#pragma unroll
      for (int dc = 0; dc < 8; ++dc) {
        bf16x8 kf = *(const bf16x8*)(krp + (((dc * 4 + g) ^ rx) << 4));
        sacc[kn] = __builtin_amdgcn_mfma_f32_16x16x32_bf16(qf[dc], kf, sacc[kn], 0, 0, 0);
      }
    }
    // ---- scale + validity mask + online softmax ----
    float mt[4];
#pragma unroll
    for (int kn = 0; kn < 4; ++kn) {
      const bool valid = (sb + kn * 16 + fr) < SEQ;
#pragma unroll
      for (int r = 0; r < 4; ++r) {
        float v = valid ? sacc[kn][r] * ATTN_SCALE : -1e9f;
        sacc[kn][r] = v;
        mt[r] = (kn == 0) ? v : fmaxf(mt[r], v);
      }
    }
#pragma unroll
    for (int r = 0; r < 4; ++r) {
#pragma unroll
      for (int off = 1; off < 16; off <<= 1)
        mt[r] = fmaxf(mt[r], __shfl_xor(mt[r], off, 64));
    }
    float corr[4];
#pragma unroll
    for (int r = 0; r < 4; ++r) {
      float mnew = fmaxf(mrow[r], mt[r]);
      corr[r] = __expf(mrow[r] - mnew);
      mrow[r] = mnew;
    }
    float psum[4] = {0.f, 0.f, 0.f, 0.f};
    char* pw = (char*)&Ps[w][0];
#pragma unroll
    for (int kn = 0; kn < 4; ++kn) {
#pragma unroll
      for (int r = 0; r < 4; ++r) {
        float p = __expf(sacc[kn][r] - mrow[r]);
        psum[r] += p;
        const int q = g * 4 + r;
        *(u16*)(pw + q * 128 + ((2 * (kn * 16 + fr)) ^ ((q & 7) << 4))) = f2b(p);
      }
    }
#pragma unroll
    for (int r = 0; r < 4; ++r) {
#pragma unroll
      for (int off = 1; off < 16; off <<= 1)
        psum[r] += __shfl_xor(psum[r], off, 64);
      lrow[r] = lrow[r] * corr[r] + psum[r];
    }
#pragma unroll
    for (int dn = 0; dn < 16; ++dn)
#pragma unroll
      for (int r = 0; r < 4; ++r) ctx[dn][r] *= corr[r];
    __syncthreads();  // Ps visible (and ordered) before fragment reads

    // ---- ctx += P * V (via Vt rows as B^T) ----
    bf16x8 pf[2];
#pragma unroll
    for (int kc = 0; kc < 2; ++kc)
      pf[kc] = *(const bf16x8*)(pw + fr * 128 + ((kc * 64 + g * 16) ^ ((fr & 7) << 4)));
#pragma unroll
    for (int dn = 0; dn < 16; ++dn) {
      const int d = dn * 16 + fr;
      const char* vrp = (const char*)Vts + d * 128;
      const int dx = d & 7;
#pragma unroll
      for (int kc = 0; kc < 2; ++kc) {
        bf16x8 vf = *(const bf16x8*)(vrp + (((kc * 4 + g) ^ dx) << 4));
        ctx[dn] = __builtin_amdgcn_mfma_f32_16x16x32_bf16(pf[kc], vf, ctx[dn], 0, 0, 0);
      }
    }
    __syncthreads();  // all waves done with Ks/Vts before next stage
  }
  // ---- epilogue: normalize and store ctx ----
  float inv[4];
#pragma unroll
  for (int r = 0; r < 4; ++r) inv[r] = 1.0f / lrow[r];
  const int qrow0 = qb * 64 + w * 16 + g * 4;
#pragma unroll
  for (int dn = 0; dn < 16; ++dn) {
#pragma unroll
    for (int r = 0; r < 4; ++r) {
      ctxw[(size_t)(n * WINL + qrow0 + r) * HDIM + h * DHEAD + dn * 16 + fr] =
          f2b(ctx[dn][r] * inv[r]);
    }
  }
}

// ---------------- overlap-average combine: ctx_avg[8192][3072] ----------------
__global__ __launch_bounds__(256) void combine_kernel(const u16* __restrict__ ctxw,
                                                      u16* __restrict__ ctx_avg) {
  int idx = blockIdx.x * 256 + threadIdx.x;
  if (idx >= SEQ * (HDIM / 8)) return;
  const int s = idx / (HDIM / 8);
  const int cc = (idx % (HDIM / 8)) * 8;
  const int w1 = s / STR;          // <= 18
  const int off1 = s - w1 * STR;   // 0..447
  us8 a = *(const us8*)(ctxw + (size_t)(w1 * WINL + off1) * HDIM + cc);
  if (w1 >= 1 && off1 < (WINL - STR)) {
    us8 b = *(const us8*)(ctxw + (size_t)((w1 - 1) * WINL + off1 + STR) * HDIM + cc);
#pragma unroll
    for (int j = 0; j < 8; ++j) a[j] = f2b(0.5f * (b2f(a[j]) + b2f(b[j])));
  }
  *(us8*)(ctx_avg + (size_t)s * HDIM + cc) = a;
}

__global__ void ws_marker(float* out, float v) { out[0] = v; }

// ---------------- launch ----------------
extern "C" void kernel_launch(void* const* d_in, const int* in_sizes, int n_in,
                              void* d_out, int out_size, void* d_ws, size_t ws_size,
                              hipStream_t stream) {
  const float* X  = (const float*)d_in[0];
  const float* Wq = (const float*)d_in[1];
  const float* bq = (const float*)d_in[2];
  const float* Wk = (const float*)d_in[3];
  const float* bk = (const float*)d_in[4];
  const float* Wv = (const float*)d_in[5];
  const float* bv = (const float*)d_in[6];
  const float* Wo = (const float*)d_in[7];
  const float* bo = (const float*)d_in[8];
  float* out = (float*)d_out;

  // workspace layout (bytes)
  const size_t OFF_XB   = 0;                          // 8192*3072*2   = 50331648
  const size_t OFF_WQKV = 50331648;                   // 9216*3072*2   = 56623104
  const size_t OFF_WO   = 106954752;                  // 3072*3072*2   = 18874368
  const size_t OFF_QKV  = 125829120;                  // 8192*9216*2   = 150994944
  const size_t OFF_VT   = 276824064;                  // 3072*8192*2   = 50331648
  const size_t OFF_BIAS = 327155712;                  // 9216*4        = 36864
  const size_t WS_NEED  = 327192576;
  if (ws_size < WS_NEED) {
    hipMemsetAsync(d_out, 0, (size_t)out_size * 4, stream);
    ws_marker<<<1, 1, 0, stream>>>(out, (float)(ws_size / 1048576));
    return;
  }
  char* ws = (char*)d_ws;
  u16* Xb      = (u16*)(ws + OFF_XB);
  u16* Wqkvb   = (u16*)(ws + OFF_WQKV);
  u16* Wob     = (u16*)(ws + OFF_WO);
  u16* QKV     = (u16*)(ws + OFF_QKV);
  u16* Vt      = (u16*)(ws + OFF_VT);
  float* biasQ = (float*)(ws + OFF_BIAS);
  u16* ctxw    = (u16*)d_out;  // 59.8MB scratch inside the 100.7MB output buffer
  u16* ctx_avg = Xb;           // alias: Xb dead after QKV GEMM

  cvt_f32_bf16<<<12288, 256, 0, stream>>>(X, Xb, SEQ * HDIM / 8);
  cvt_f32_bf16<<<4608, 256, 0, stream>>>(Wq, Wqkvb, HDIM * HDIM / 8);
  cvt_f32_bf16<<<4608, 256, 0, stream>>>(Wk, Wqkvb + (size_t)HDIM * HDIM, HDIM * HDIM / 8);
  cvt_f32_bf16<<<4608, 256, 0, stream>>>(Wv, Wqkvb + (size_t)2 * HDIM * HDIM, HDIM * HDIM / 8);
  cvt_f32_bf16<<<4608, 256, 0, stream>>>(Wo, Wob, HDIM * HDIM / 8);
  biascat<<<36, 256, 0, stream>>>(bq, bk, bv, biasQ);

  gemm256<true><<<dim3((SEQ / 256) * (QKVN / 256)), 512, 0, stream>>>(
      Xb, Wqkvb, biasQ, nullptr, QKV, QKVN, HDIM);

  vtrans<<<dim3(SEQ / 64, HDIM / 64), 256, 0, stream>>>(QKV, Vt);

  attn_kernel<<<dim3(8, NHEAD, NWIN), 256, 0, stream>>>(QKV, Vt, ctxw);

  combine_kernel<<<12288, 256, 0, stream>>>(ctxw, ctx_avg);

  gemm256<false><<<dim3((SEQ / 256) * (HDIM / 256)), 512, 0, stream>>>(
      ctx_avg, Wob, bo, out, nullptr, HDIM, HDIM);
}